// Round 1
// baseline (841.769 us; speedup 1.0000x reference)
//
#include <hip/hip_runtime.h>
#include <math.h>

// Problem constants (fixed by the reference).
constexpr int Nn = 50000;   // nodes
constexpr int Ee = 800000;  // edges
constexpr int Dd = 128;     // feature dim
constexpr int Gg = 64;      // graphs
constexpr float SCALE = 0.08838834764831845f; // 1/sqrt(128)

// ---------------- CSR build (sort edges by dst) ----------------

__global__ __launch_bounds__(256) void hist_kernel(const int* __restrict__ dst,
                                                   int* __restrict__ counts) {
    int e = blockIdx.x * 256 + threadIdx.x;
    if (e < Ee) atomicAdd(&counts[dst[e]], 1);
}

__global__ __launch_bounds__(256) void scan1_kernel(const int* __restrict__ counts,
                                                    int* __restrict__ offsets,
                                                    int* __restrict__ blockSums) {
    __shared__ int sh[256];
    int i = blockIdx.x * 256 + threadIdx.x;
    int v = (i < Nn) ? counts[i] : 0;
    sh[threadIdx.x] = v;
    __syncthreads();
    for (int off = 1; off < 256; off <<= 1) {
        int t = (threadIdx.x >= off) ? sh[threadIdx.x - off] : 0;
        __syncthreads();
        sh[threadIdx.x] += t;
        __syncthreads();
    }
    if (i < Nn) offsets[i] = sh[threadIdx.x] - v;   // exclusive within block
    if (threadIdx.x == 255) blockSums[blockIdx.x] = sh[255];
}

__global__ __launch_bounds__(256) void scan2_kernel(int* __restrict__ blockSums, int nb) {
    __shared__ int sh[256];
    int t = threadIdx.x;
    int v = (t < nb) ? blockSums[t] : 0;
    sh[t] = v;
    __syncthreads();
    for (int off = 1; off < 256; off <<= 1) {
        int u = (t >= off) ? sh[t - off] : 0;
        __syncthreads();
        sh[t] += u;
        __syncthreads();
    }
    if (t < nb) blockSums[t] = sh[t] - v;           // exclusive across blocks
}

__global__ __launch_bounds__(256) void scan3_kernel(int* __restrict__ offsets,
                                                    const int* __restrict__ blockSums,
                                                    int* __restrict__ cursor) {
    int i = blockIdx.x * 256 + threadIdx.x;
    if (i < Nn) {
        int o = offsets[i] + blockSums[blockIdx.x];
        offsets[i] = o;
        cursor[i] = o;
    }
    if (i == 0) offsets[Nn] = Ee;
}

__global__ __launch_bounds__(256) void scatter_kernel(const int* __restrict__ src,
                                                      const int* __restrict__ dst,
                                                      int* __restrict__ cursor,
                                                      int* __restrict__ sorted_src) {
    int e = blockIdx.x * 256 + threadIdx.x;
    if (e < Ee) {
        int d = dst[e];
        int pos = atomicAdd(&cursor[d], 1);
        sorted_src[pos] = src[e];
    }
}

// ---------------- fused 4-way projection GEMM: Y = X @ W^T + b ----------------
// Output tile 64 rows x 64 cols; 8 col-tiles cover {q,k,v,skip} (2 tiles each).

__global__ __launch_bounds__(256) void gemm4_kernel(const float* __restrict__ X,
    const float* __restrict__ W0, const float* __restrict__ W1,
    const float* __restrict__ W2, const float* __restrict__ W3,
    const float* __restrict__ b0, const float* __restrict__ b1,
    const float* __restrict__ b2, const float* __restrict__ b3,
    float* __restrict__ O0, float* __restrict__ O1,
    float* __restrict__ O2, float* __restrict__ O3) {
    __shared__ float Xs[64][132];   // +4 pad: float4-aligned, rotates banks per row
    __shared__ float Wt[64][132];
    int tid = threadIdx.x;
    int rowBase = blockIdx.x * 64;
    int cb = blockIdx.y;            // 0..7
    int which = cb >> 1;
    int colOff = (cb & 1) * 64;
    const float* Wsel = (which == 0) ? W0 : (which == 1) ? W1 : (which == 2) ? W2 : W3;
    const float* bsel = (which == 0) ? b0 : (which == 1) ? b1 : (which == 2) ? b2 : b3;
    float*       Osel = (which == 0) ? O0 : (which == 1) ? O1 : (which == 2) ? O2 : O3;

#pragma unroll
    for (int t = 0; t < 8; ++t) {
        int i = tid + t * 256;          // 0..2047 float4 slots
        int r = i >> 5;
        int c4 = (i & 31) * 4;
        int gr = rowBase + r;
        float4 xv = make_float4(0.f, 0.f, 0.f, 0.f);
        if (gr < Nn) xv = *(const float4*)(X + (size_t)gr * 128 + c4);
        *(float4*)&Xs[r][c4] = xv;
        *(float4*)&Wt[r][c4] = *(const float4*)(Wsel + (size_t)(colOff + r) * 128 + c4);
    }
    __syncthreads();

    int tx = tid & 15, ty = tid >> 4;
    float acc[4][4];
#pragma unroll
    for (int i = 0; i < 4; ++i)
#pragma unroll
        for (int j = 0; j < 4; ++j) acc[i][j] = 0.f;

#pragma unroll 8
    for (int k4 = 0; k4 < 128; k4 += 4) {
        float4 av[4], bv[4];
#pragma unroll
        for (int i = 0; i < 4; ++i) av[i] = *(const float4*)&Xs[ty * 4 + i][k4];
#pragma unroll
        for (int j = 0; j < 4; ++j) bv[j] = *(const float4*)&Wt[tx * 4 + j][k4];
#pragma unroll
        for (int i = 0; i < 4; ++i)
#pragma unroll
            for (int j = 0; j < 4; ++j)
                acc[i][j] += av[i].x * bv[j].x + av[i].y * bv[j].y +
                             av[i].z * bv[j].z + av[i].w * bv[j].w;
    }

    int col = colOff + tx * 4;
    float4 bb = *(const float4*)(bsel + col);
#pragma unroll
    for (int i = 0; i < 4; ++i) {
        int gr = rowBase + ty * 4 + i;
        if (gr < Nn) {
            float4 o = make_float4(acc[i][0] + bb.x, acc[i][1] + bb.y,
                                   acc[i][2] + bb.z, acc[i][3] + bb.w);
            *(float4*)(Osel + (size_t)gr * 128 + col) = o;
        }
    }
}

// ---------------- fused per-node attention (flash-style online softmax) ----------------
// One 64-lane wave per destination node. No atomics: edges pre-sorted by dst.

__global__ __launch_bounds__(256) void attn_kernel(const float* __restrict__ q,
                                                   const float* __restrict__ k,
                                                   const float* __restrict__ v,
                                                   const float* __restrict__ s,
                                                   const int* __restrict__ offsets,
                                                   const int* __restrict__ sorted_src,
                                                   float* __restrict__ h) {
    int wid = blockIdx.x * 4 + (threadIdx.x >> 6);
    int lane = threadIdx.x & 63;
    if (wid >= Nn) return;
    float2 qv = ((const float2*)(q + (size_t)wid * Dd))[lane];
    int beg = offsets[wid], end = offsets[wid + 1];
    float m = -INFINITY, l = 0.f;
    float2 acc = make_float2(0.f, 0.f);
    for (int e = beg; e < end; ++e) {
        int sidx = sorted_src[e];
        float2 kv = ((const float2*)(k + (size_t)sidx * Dd))[lane];
        float part = qv.x * kv.x + qv.y * kv.y;
#pragma unroll
        for (int off = 32; off > 0; off >>= 1) part += __shfl_xor(part, off, 64);
        float a = part * SCALE;
        float mn = fmaxf(m, a);
        float so = __expf(m - mn);   // 0 on first edge (m = -inf)
        float pw = __expf(a - mn);
        l = l * so + pw;
        float2 vv = ((const float2*)(v + (size_t)sidx * Dd))[lane];
        acc.x = acc.x * so + pw * vv.x;
        acc.y = acc.y * so + pw * vv.y;
        m = mn;
    }
    float inv = (l > 0.f) ? (1.0f / l) : 0.f;   // deg==0 -> pure skip
    float2 sk = ((const float2*)(s + (size_t)wid * Dd))[lane];
    float2 o;
    o.x = fmaxf(acc.x * inv + sk.x, 0.f);       // + skip, ReLU
    o.y = fmaxf(acc.y * inv + sk.y, 0.f);
    ((float2*)(h + (size_t)wid * Dd))[lane] = o;
}

// ---------------- pooling + classifier ----------------

__global__ __launch_bounds__(256) void bound_kernel(const int* __restrict__ batch,
                                                    int* __restrict__ startg,
                                                    int* __restrict__ endg) {
    int n = blockIdx.x * 256 + threadIdx.x;
    if (n >= Nn) return;
    int g = batch[n];
    if (n == Nn - 1 || batch[n + 1] != g) endg[g] = n + 1;
    if (n == 0 || batch[n - 1] != g) startg[g] = n;
}

__global__ __launch_bounds__(128) void pool_kernel(const float* __restrict__ h,
                                                   const int* __restrict__ batch,
                                                   float* __restrict__ pooled) {
    int c = threadIdx.x;            // 0..127 (column)
    int n0 = blockIdx.x * 128;
    int nend = min(n0 + 128, Nn);
    int curg = batch[n0];           // batch is sorted -> few segments per block
    float sum = 0.f;
    for (int n = n0; n < nend; ++n) {
        int g = batch[n];
        if (g != curg) {
            atomicAdd(&pooled[curg * Dd + c], sum);
            sum = 0.f;
            curg = g;
        }
        sum += h[(size_t)n * Dd + c];
    }
    atomicAdd(&pooled[curg * Dd + c], sum);
}

__global__ __launch_bounds__(64) void mlp_kernel(const float* __restrict__ pooled,
                                                 const int* __restrict__ startg,
                                                 const int* __restrict__ endg,
                                                 const float* __restrict__ Wc1,
                                                 const float* __restrict__ bc1,
                                                 const float* __restrict__ Wc2,
                                                 const float* __restrict__ bc2,
                                                 float* __restrict__ out) {
    __shared__ float pm[128];
    __shared__ float hid[64];
    int g = blockIdx.x, t = threadIdx.x;   // 64 threads
    float cnt = fmaxf((float)(endg[g] - startg[g]), 1.0f);
    float invc = 1.0f / cnt;
    pm[t]      = pooled[g * 128 + t] * invc;
    pm[t + 64] = pooled[g * 128 + 64 + t] * invc;
    __syncthreads();
    float acc = bc1[t];
    for (int i = 0; i < 128; ++i) acc += pm[i] * Wc1[t * 128 + i];
    hid[t] = fmaxf(acc, 0.f);
    __syncthreads();
    if (t < 2) {
        float a = bc2[t];
        for (int i = 0; i < 64; ++i) a += hid[i] * Wc2[t * 64 + i];
        out[g * 2 + t] = a;
    }
}

// ---------------- launch ----------------

extern "C" void kernel_launch(void* const* d_in, const int* in_sizes, int n_in,
                              void* d_out, int out_size, void* d_ws, size_t ws_size,
                              hipStream_t stream) {
    const float* x   = (const float*)d_in[0];
    const int*   ei  = (const int*)d_in[1];
    const int* batch = (const int*)d_in[2];
    // setup_inputs dict order: per layer Wq,Wk,Wv,Ws then bq,bk,bv,bs.
    const float* W[2][4];
    const float* B[2][4];
    for (int l = 0; l < 2; ++l) {
        for (int j = 0; j < 4; ++j) W[l][j] = (const float*)d_in[3 + l * 8 + j];
        for (int j = 0; j < 4; ++j) B[l][j] = (const float*)d_in[3 + l * 8 + 4 + j];
    }
    const float* Wc1 = (const float*)d_in[19];
    const float* bc1 = (const float*)d_in[20];
    const float* Wc2 = (const float*)d_in[21];
    const float* bc2 = (const float*)d_in[22];
    float* out = (float*)d_out;

    const int* src = ei;        // edge_index[0]
    const int* dst = ei + Ee;   // edge_index[1]

    char* p = (char*)d_ws;
    auto alloc = [&](size_t bytes) {
        void* r = (void*)p;
        p += (bytes + 255) & ~(size_t)255;
        return r;
    };
    float* q  = (float*)alloc((size_t)Nn * Dd * 4);
    float* kk = (float*)alloc((size_t)Nn * Dd * 4);
    float* vv = (float*)alloc((size_t)Nn * Dd * 4);
    float* ss = (float*)alloc((size_t)Nn * Dd * 4);
    float* h  = (float*)alloc((size_t)Nn * Dd * 4);
    char* zbase = p;  // region zeroed each launch
    int*   counts = (int*)alloc(Nn * 4);
    int*   startg = (int*)alloc(Gg * 4);
    int*   endg   = (int*)alloc(Gg * 4);
    float* pooled = (float*)alloc(Gg * Dd * 4);
    size_t zbytes = (size_t)(p - zbase);
    int* offsets    = (int*)alloc((size_t)(Nn + 1) * 4);
    int* cursor     = (int*)alloc(Nn * 4);
    int* blockSums  = (int*)alloc(256 * 4);
    int* sorted_src = (int*)alloc((size_t)Ee * 4);

    hipMemsetAsync(zbase, 0, zbytes, stream);

    constexpr int NB = (Nn + 255) / 256;  // 196 scan blocks (fits single-block pass 2)
    hist_kernel<<<(Ee + 255) / 256, 256, 0, stream>>>(dst, counts);
    scan1_kernel<<<NB, 256, 0, stream>>>(counts, offsets, blockSums);
    scan2_kernel<<<1, 256, 0, stream>>>(blockSums, NB);
    scan3_kernel<<<NB, 256, 0, stream>>>(offsets, blockSums, cursor);
    scatter_kernel<<<(Ee + 255) / 256, 256, 0, stream>>>(src, dst, cursor, sorted_src);

    dim3 ggrid((Nn + 63) / 64, 8);
    // layer 0
    gemm4_kernel<<<ggrid, 256, 0, stream>>>(x, W[0][0], W[0][1], W[0][2], W[0][3],
                                            B[0][0], B[0][1], B[0][2], B[0][3],
                                            q, kk, vv, ss);
    attn_kernel<<<(Nn + 3) / 4, 256, 0, stream>>>(q, kk, vv, ss, offsets, sorted_src, h);
    // layer 1 (reads h, overwrites h after projections are done)
    gemm4_kernel<<<ggrid, 256, 0, stream>>>(h, W[1][0], W[1][1], W[1][2], W[1][3],
                                            B[1][0], B[1][1], B[1][2], B[1][3],
                                            q, kk, vv, ss);
    attn_kernel<<<(Nn + 3) / 4, 256, 0, stream>>>(q, kk, vv, ss, offsets, sorted_src, h);

    bound_kernel<<<(Nn + 255) / 256, 256, 0, stream>>>(batch, startg, endg);
    pool_kernel<<<(Nn + 127) / 128, 128, 0, stream>>>(h, batch, pooled);
    mlp_kernel<<<Gg, 64, 0, stream>>>(pooled, startg, endg, Wc1, bc1, Wc2, bc2, out);
}

// Round 2
// 835.942 us; speedup vs baseline: 1.0070x; 1.0070x over previous
//
#include <hip/hip_runtime.h>
#include <math.h>

// Problem constants (fixed by the reference).
constexpr int Nn = 50000;   // nodes
constexpr int Ee = 800000;  // edges
constexpr int Dd = 128;     // feature dim
constexpr int Gg = 64;      // graphs
constexpr float SCALE = 0.08838834764831845f; // 1/sqrt(128)

// ---------------- CSR build (sort edges by dst) ----------------

__global__ __launch_bounds__(256) void hist_kernel(const int* __restrict__ dst,
                                                   int* __restrict__ counts) {
    int e = blockIdx.x * 256 + threadIdx.x;
    if (e < Ee) atomicAdd(&counts[dst[e]], 1);
}

__global__ __launch_bounds__(256) void scan1_kernel(const int* __restrict__ counts,
                                                    int* __restrict__ offsets,
                                                    int* __restrict__ blockSums) {
    __shared__ int sh[256];
    int i = blockIdx.x * 256 + threadIdx.x;
    int v = (i < Nn) ? counts[i] : 0;
    sh[threadIdx.x] = v;
    __syncthreads();
    for (int off = 1; off < 256; off <<= 1) {
        int t = (threadIdx.x >= off) ? sh[threadIdx.x - off] : 0;
        __syncthreads();
        sh[threadIdx.x] += t;
        __syncthreads();
    }
    if (i < Nn) offsets[i] = sh[threadIdx.x] - v;   // exclusive within block
    if (threadIdx.x == 255) blockSums[blockIdx.x] = sh[255];
}

__global__ __launch_bounds__(256) void scan2_kernel(int* __restrict__ blockSums, int nb) {
    __shared__ int sh[256];
    int t = threadIdx.x;
    int v = (t < nb) ? blockSums[t] : 0;
    sh[t] = v;
    __syncthreads();
    for (int off = 1; off < 256; off <<= 1) {
        int u = (t >= off) ? sh[t - off] : 0;
        __syncthreads();
        sh[t] += u;
        __syncthreads();
    }
    if (t < nb) blockSums[t] = sh[t] - v;           // exclusive across blocks
}

__global__ __launch_bounds__(256) void scan3_kernel(int* __restrict__ offsets,
                                                    const int* __restrict__ blockSums,
                                                    int* __restrict__ cursor) {
    int i = blockIdx.x * 256 + threadIdx.x;
    if (i < Nn) {
        int o = offsets[i] + blockSums[blockIdx.x];
        offsets[i] = o;
        cursor[i] = o;
    }
    if (i == 0) offsets[Nn] = Ee;
}

__global__ __launch_bounds__(256) void scatter_kernel(const int* __restrict__ src,
                                                      const int* __restrict__ dst,
                                                      int* __restrict__ cursor,
                                                      int* __restrict__ sorted_src) {
    int e = blockIdx.x * 256 + threadIdx.x;
    if (e < Ee) {
        int d = dst[e];
        int pos = atomicAdd(&cursor[d], 1);
        sorted_src[pos] = src[e];
    }
}

// ---------------- fused 4-way projection GEMM: Y = X @ W^T + b ----------------
// One block owns 64 rows; stages X ONCE, loops over all 8 weight col-tiles.
// Fragment mapping is STRIDED (tx + j*16) so LDS reads are 2-way max (free).

__global__ __launch_bounds__(256) void gemm4_kernel(const float* __restrict__ X,
    const float* __restrict__ W0, const float* __restrict__ W1,
    const float* __restrict__ W2, const float* __restrict__ W3,
    const float* __restrict__ b0, const float* __restrict__ b1,
    const float* __restrict__ b2, const float* __restrict__ b3,
    float* __restrict__ O0, float* __restrict__ O1,
    float* __restrict__ O2, float* __restrict__ O3) {
    __shared__ float Xs[64][132];   // LD=132: row stride = 4 banks -> strided reads spread
    __shared__ float Wt[64][132];
    int tid = threadIdx.x;
    int rowBase = blockIdx.x * 64;

    // stage X tile once (64 rows x 128 cols, float4)
#pragma unroll
    for (int t = 0; t < 8; ++t) {
        int i = tid + t * 256;          // 2048 float4 slots
        int r = i >> 5;
        int c4 = (i & 31) * 4;
        int gr = rowBase + r;
        float4 xv = make_float4(0.f, 0.f, 0.f, 0.f);
        if (gr < Nn) xv = *(const float4*)(X + (size_t)gr * 128 + c4);
        *(float4*)&Xs[r][c4] = xv;
    }

    int tx = tid & 15, ty = tid >> 4;
    const float* Ws[4] = {W0, W1, W2, W3};
    const float* Bs[4] = {b0, b1, b2, b3};
    float*       Os[4] = {O0, O1, O2, O3};

    for (int cb = 0; cb < 8; ++cb) {
        int which = cb >> 1;
        int colOff = (cb & 1) * 64;
        const float* Wsel = Ws[which];
        __syncthreads();                 // protect Wt from previous tile's readers
#pragma unroll
        for (int t = 0; t < 8; ++t) {
            int i = tid + t * 256;
            int r = i >> 5;
            int c4 = (i & 31) * 4;
            *(float4*)&Wt[r][c4] = *(const float4*)(Wsel + (size_t)(colOff + r) * 128 + c4);
        }
        __syncthreads();

        float acc[4][4];
#pragma unroll
        for (int i = 0; i < 4; ++i)
#pragma unroll
            for (int j = 0; j < 4; ++j) acc[i][j] = 0.f;

#pragma unroll 8
        for (int k4 = 0; k4 < 128; k4 += 4) {
            float4 av[4], bv[4];
#pragma unroll
            for (int i = 0; i < 4; ++i) av[i] = *(const float4*)&Xs[ty + i * 16][k4];
#pragma unroll
            for (int j = 0; j < 4; ++j) bv[j] = *(const float4*)&Wt[tx + j * 16][k4];
#pragma unroll
            for (int i = 0; i < 4; ++i)
#pragma unroll
                for (int j = 0; j < 4; ++j)
                    acc[i][j] += av[i].x * bv[j].x + av[i].y * bv[j].y +
                                 av[i].z * bv[j].z + av[i].w * bv[j].w;
        }

        const float* bsel = Bs[which];
        float*       Osel = Os[which];
        float bb[4];
#pragma unroll
        for (int j = 0; j < 4; ++j) bb[j] = bsel[colOff + tx + j * 16];
#pragma unroll
        for (int i = 0; i < 4; ++i) {
            int gr = rowBase + ty + i * 16;
            if (gr < Nn) {
#pragma unroll
                for (int j = 0; j < 4; ++j)
                    Osel[(size_t)gr * 128 + colOff + tx + j * 16] = acc[i][j] + bb[j];
            }
        }
    }
}

// ---------------- fused per-node attention (two-pass per chunk) ----------------
// One 64-lane wave per node, split into 2 groups of 32 lanes (float4 each = 128 dims,
// 2 edges in flight). Scores stashed in LDS; pass 2 has no serial rescale chain.

constexpr int CHUNK = 128;  // Poisson(16) max degree ~45; chunk loop keeps it correct anyway

__global__ __launch_bounds__(256) void attn_kernel(const float* __restrict__ q,
                                                   const float* __restrict__ k,
                                                   const float* __restrict__ v,
                                                   const float* __restrict__ s,
                                                   const int* __restrict__ offsets,
                                                   const int* __restrict__ sorted_src,
                                                   float* __restrict__ h) {
    __shared__ float astash[4][CHUNK];
    int wslot = threadIdx.x >> 6;
    int wid = blockIdx.x * 4 + wslot;
    if (wid >= Nn) return;
    int lane = threadIdx.x & 63;
    int gid = lane >> 5;         // group 0/1 (edge parity)
    int gl = lane & 31;          // lane within group, holds 4 dims
    const float4 qv = ((const float4*)(q + (size_t)wid * Dd))[gl];
    int beg = offsets[wid], end = offsets[wid + 1];

    float m = -INFINITY, l = 0.f;
    float4 acc = make_float4(0.f, 0.f, 0.f, 0.f);

    for (int cbeg = beg; cbeg < end; cbeg += CHUNK) {
        int cend = min(cbeg + CHUNK, end);
        float cm = -INFINITY;
        // pass 1: scores for this chunk (each group does its parity; no cross-group LDS dep)
        for (int e = cbeg + gid; e < cend; e += 2) {
            int sidx = sorted_src[e];
            float4 kv = ((const float4*)(k + (size_t)sidx * Dd))[gl];
            float part = qv.x * kv.x + qv.y * kv.y + qv.z * kv.z + qv.w * kv.w;
#pragma unroll
            for (int off = 16; off > 0; off >>= 1) part += __shfl_xor(part, off, 64);
            float a = part * SCALE;
            if (gl == 0) astash[wslot][e - cbeg] = a;
            cm = fmaxf(cm, a);
        }
        cm = fmaxf(cm, __shfl_xor(cm, 32, 64));
        float mn = fmaxf(m, cm);
        float sc = (m > -INFINITY) ? __expf(m - mn) : 0.f;  // once per chunk, not per edge
        l *= sc; acc.x *= sc; acc.y *= sc; acc.z *= sc; acc.w *= sc;
        // pass 2: weights + V accumulation (independent iterations)
        for (int e = cbeg + gid; e < cend; e += 2) {
            float w = __expf(astash[wslot][e - cbeg] - mn);
            int sidx = sorted_src[e];
            float4 vv = ((const float4*)(v + (size_t)sidx * Dd))[gl];
            l += w;
            acc.x += w * vv.x; acc.y += w * vv.y;
            acc.z += w * vv.z; acc.w += w * vv.w;
        }
        m = mn;
    }

    // combine the two groups' partial sums
    l += __shfl_xor(l, 32, 64);
    acc.x += __shfl_xor(acc.x, 32, 64);
    acc.y += __shfl_xor(acc.y, 32, 64);
    acc.z += __shfl_xor(acc.z, 32, 64);
    acc.w += __shfl_xor(acc.w, 32, 64);

    if (gid == 0) {
        float inv = (l > 0.f) ? (1.0f / l) : 0.f;   // deg==0 -> pure skip
        float4 sk = ((const float4*)(s + (size_t)wid * Dd))[gl];
        float4 o;
        o.x = fmaxf(acc.x * inv + sk.x, 0.f);       // + skip, ReLU
        o.y = fmaxf(acc.y * inv + sk.y, 0.f);
        o.z = fmaxf(acc.z * inv + sk.z, 0.f);
        o.w = fmaxf(acc.w * inv + sk.w, 0.f);
        ((float4*)(h + (size_t)wid * Dd))[gl] = o;
    }
}

// ---------------- pooling + classifier ----------------

__global__ __launch_bounds__(256) void bound_kernel(const int* __restrict__ batch,
                                                    int* __restrict__ startg,
                                                    int* __restrict__ endg) {
    int n = blockIdx.x * 256 + threadIdx.x;
    if (n >= Nn) return;
    int g = batch[n];
    if (n == Nn - 1 || batch[n + 1] != g) endg[g] = n + 1;
    if (n == 0 || batch[n - 1] != g) startg[g] = n;
}

__global__ __launch_bounds__(128) void pool_kernel(const float* __restrict__ h,
                                                   const int* __restrict__ batch,
                                                   float* __restrict__ pooled) {
    int c = threadIdx.x;            // 0..127 (column)
    int n0 = blockIdx.x * 128;
    int nend = min(n0 + 128, Nn);
    int curg = batch[n0];           // batch is sorted -> few segments per block
    float sum = 0.f;
    for (int n = n0; n < nend; ++n) {
        int g = batch[n];
        if (g != curg) {
            atomicAdd(&pooled[curg * Dd + c], sum);
            sum = 0.f;
            curg = g;
        }
        sum += h[(size_t)n * Dd + c];
    }
    atomicAdd(&pooled[curg * Dd + c], sum);
}

__global__ __launch_bounds__(64) void mlp_kernel(const float* __restrict__ pooled,
                                                 const int* __restrict__ startg,
                                                 const int* __restrict__ endg,
                                                 const float* __restrict__ Wc1,
                                                 const float* __restrict__ bc1,
                                                 const float* __restrict__ Wc2,
                                                 const float* __restrict__ bc2,
                                                 float* __restrict__ out) {
    __shared__ float pm[128];
    __shared__ float hid[64];
    int g = blockIdx.x, t = threadIdx.x;   // 64 threads
    float cnt = fmaxf((float)(endg[g] - startg[g]), 1.0f);
    float invc = 1.0f / cnt;
    pm[t]      = pooled[g * 128 + t] * invc;
    pm[t + 64] = pooled[g * 128 + 64 + t] * invc;
    __syncthreads();
    float acc = bc1[t];
    for (int i = 0; i < 128; ++i) acc += pm[i] * Wc1[t * 128 + i];
    hid[t] = fmaxf(acc, 0.f);
    __syncthreads();
    if (t < 2) {
        float a = bc2[t];
        for (int i = 0; i < 64; ++i) a += hid[i] * Wc2[t * 64 + i];
        out[g * 2 + t] = a;
    }
}

// ---------------- launch ----------------

extern "C" void kernel_launch(void* const* d_in, const int* in_sizes, int n_in,
                              void* d_out, int out_size, void* d_ws, size_t ws_size,
                              hipStream_t stream) {
    const float* x   = (const float*)d_in[0];
    const int*   ei  = (const int*)d_in[1];
    const int* batch = (const int*)d_in[2];
    // setup_inputs dict order: per layer Wq,Wk,Wv,Ws then bq,bk,bv,bs.
    const float* W[2][4];
    const float* B[2][4];
    for (int l = 0; l < 2; ++l) {
        for (int j = 0; j < 4; ++j) W[l][j] = (const float*)d_in[3 + l * 8 + j];
        for (int j = 0; j < 4; ++j) B[l][j] = (const float*)d_in[3 + l * 8 + 4 + j];
    }
    const float* Wc1 = (const float*)d_in[19];
    const float* bc1 = (const float*)d_in[20];
    const float* Wc2 = (const float*)d_in[21];
    const float* bc2 = (const float*)d_in[22];
    float* out = (float*)d_out;

    const int* src = ei;        // edge_index[0]
    const int* dst = ei + Ee;   // edge_index[1]

    char* p = (char*)d_ws;
    auto alloc = [&](size_t bytes) {
        void* r = (void*)p;
        p += (bytes + 255) & ~(size_t)255;
        return r;
    };
    float* q  = (float*)alloc((size_t)Nn * Dd * 4);
    float* kk = (float*)alloc((size_t)Nn * Dd * 4);
    float* vv = (float*)alloc((size_t)Nn * Dd * 4);
    float* ss = (float*)alloc((size_t)Nn * Dd * 4);
    float* h  = (float*)alloc((size_t)Nn * Dd * 4);
    char* zbase = p;  // region zeroed each launch
    int*   counts = (int*)alloc(Nn * 4);
    int*   startg = (int*)alloc(Gg * 4);
    int*   endg   = (int*)alloc(Gg * 4);
    float* pooled = (float*)alloc(Gg * Dd * 4);
    size_t zbytes = (size_t)(p - zbase);
    int* offsets    = (int*)alloc((size_t)(Nn + 1) * 4);
    int* cursor     = (int*)alloc(Nn * 4);
    int* blockSums  = (int*)alloc(256 * 4);
    int* sorted_src = (int*)alloc((size_t)Ee * 4);

    hipMemsetAsync(zbase, 0, zbytes, stream);

    constexpr int NB = (Nn + 255) / 256;  // 196 scan blocks (fits single-block pass 2)
    hist_kernel<<<(Ee + 255) / 256, 256, 0, stream>>>(dst, counts);
    scan1_kernel<<<NB, 256, 0, stream>>>(counts, offsets, blockSums);
    scan2_kernel<<<1, 256, 0, stream>>>(blockSums, NB);
    scan3_kernel<<<NB, 256, 0, stream>>>(offsets, blockSums, cursor);
    scatter_kernel<<<(Ee + 255) / 256, 256, 0, stream>>>(src, dst, cursor, sorted_src);

    int ggrid = (Nn + 63) / 64;
    // layer 0
    gemm4_kernel<<<ggrid, 256, 0, stream>>>(x, W[0][0], W[0][1], W[0][2], W[0][3],
                                            B[0][0], B[0][1], B[0][2], B[0][3],
                                            q, kk, vv, ss);
    attn_kernel<<<(Nn + 3) / 4, 256, 0, stream>>>(q, kk, vv, ss, offsets, sorted_src, h);
    // layer 1 (reads h, overwrites h after projections are done)
    gemm4_kernel<<<ggrid, 256, 0, stream>>>(h, W[1][0], W[1][1], W[1][2], W[1][3],
                                            B[1][0], B[1][1], B[1][2], B[1][3],
                                            q, kk, vv, ss);
    attn_kernel<<<(Nn + 3) / 4, 256, 0, stream>>>(q, kk, vv, ss, offsets, sorted_src, h);

    bound_kernel<<<(Nn + 255) / 256, 256, 0, stream>>>(batch, startg, endg);
    pool_kernel<<<(Nn + 127) / 128, 128, 0, stream>>>(h, batch, pooled);
    mlp_kernel<<<Gg, 64, 0, stream>>>(pooled, startg, endg, Wc1, bc1, Wc2, bc2, out);
}

// Round 3
// 654.552 us; speedup vs baseline: 1.2860x; 1.2771x over previous
//
#include <hip/hip_runtime.h>
#include <math.h>

typedef __bf16 bf16x8 __attribute__((ext_vector_type(8)));
typedef float  f32x4  __attribute__((ext_vector_type(4)));
typedef unsigned short ushort_t;

// Problem constants (fixed by the reference).
constexpr int Nn = 50000;   // nodes
constexpr int Ee = 800000;  // edges
constexpr int Dd = 128;     // feature dim
constexpr int Gg = 64;      // graphs
constexpr float SCALE = 0.08838834764831845f; // 1/sqrt(128)

__device__ inline ushort_t f2bf(float f) {
    unsigned u = __float_as_uint(f);
    unsigned r = (u + 0x7FFF + ((u >> 16) & 1)) >> 16;   // RNE truncate to bf16
    return (ushort_t)r;
}
__device__ inline float bf2f(ushort_t b) { return __uint_as_float(((unsigned)b) << 16); }

// ---------------- CSR build (sort edges by dst) ----------------

__global__ __launch_bounds__(256) void hist_kernel(const int* __restrict__ dst,
                                                   int* __restrict__ counts) {
    int e = blockIdx.x * 256 + threadIdx.x;
    if (e < Ee) atomicAdd(&counts[dst[e]], 1);
}

__global__ __launch_bounds__(256) void scan1_kernel(const int* __restrict__ counts,
                                                    int* __restrict__ offsets,
                                                    int* __restrict__ blockSums) {
    __shared__ int sh[256];
    int i = blockIdx.x * 256 + threadIdx.x;
    int v = (i < Nn) ? counts[i] : 0;
    sh[threadIdx.x] = v;
    __syncthreads();
    for (int off = 1; off < 256; off <<= 1) {
        int t = (threadIdx.x >= off) ? sh[threadIdx.x - off] : 0;
        __syncthreads();
        sh[threadIdx.x] += t;
        __syncthreads();
    }
    if (i < Nn) offsets[i] = sh[threadIdx.x] - v;   // exclusive within block
    if (threadIdx.x == 255) blockSums[blockIdx.x] = sh[255];
}

__global__ __launch_bounds__(256) void scan2_kernel(int* __restrict__ blockSums, int nb) {
    __shared__ int sh[256];
    int t = threadIdx.x;
    int v = (t < nb) ? blockSums[t] : 0;
    sh[t] = v;
    __syncthreads();
    for (int off = 1; off < 256; off <<= 1) {
        int u = (t >= off) ? sh[t - off] : 0;
        __syncthreads();
        sh[t] += u;
        __syncthreads();
    }
    if (t < nb) blockSums[t] = sh[t] - v;           // exclusive across blocks
}

__global__ __launch_bounds__(256) void scan3_kernel(int* __restrict__ offsets,
                                                    const int* __restrict__ blockSums,
                                                    int* __restrict__ cursor) {
    int i = blockIdx.x * 256 + threadIdx.x;
    if (i < Nn) {
        int o = offsets[i] + blockSums[blockIdx.x];
        offsets[i] = o;
        cursor[i] = o;
    }
    if (i == 0) offsets[Nn] = Ee;
}

__global__ __launch_bounds__(256) void scatter_kernel(const int* __restrict__ src,
                                                      const int* __restrict__ dst,
                                                      int* __restrict__ cursor,
                                                      int* __restrict__ sorted_src) {
    int e = blockIdx.x * 256 + threadIdx.x;
    if (e < Ee) {
        int d = dst[e];
        int pos = atomicAdd(&cursor[d], 1);
        sorted_src[pos] = src[e];
    }
}

// ---------------- split-bf16 conversion ----------------
// x = hi + lo, both bf16; residual |x|*2^-18.

__global__ __launch_bounds__(256) void convx_kernel(const float* __restrict__ X,
                                                    ushort_t* __restrict__ Xh,
                                                    ushort_t* __restrict__ Xl,
                                                    int n4) {
    int i = blockIdx.x * 256 + threadIdx.x;
    if (i >= n4) return;
    float4 x = ((const float4*)X)[i];
    ushort4 h, l;
    h.x = f2bf(x.x); l.x = f2bf(x.x - bf2f(h.x));
    h.y = f2bf(x.y); l.y = f2bf(x.y - bf2f(h.y));
    h.z = f2bf(x.z); l.z = f2bf(x.z - bf2f(h.z));
    h.w = f2bf(x.w); l.w = f2bf(x.w - bf2f(h.w));
    ((ushort4*)Xh)[i] = h;
    ((ushort4*)Xl)[i] = l;
}

// Convert all 8 weight matrices (2 layers x {q,k,v,s}) in one launch.
__global__ __launch_bounds__(256) void convw_kernel(
    const float* w0, const float* w1, const float* w2, const float* w3,
    const float* w4, const float* w5, const float* w6, const float* w7,
    ushort_t* __restrict__ Wh, ushort_t* __restrict__ Wl) {
    const float* ws[8] = {w0, w1, w2, w3, w4, w5, w6, w7};
    int m = blockIdx.x >> 4;                       // 16 blocks per 16384-elem matrix
    int off = (blockIdx.x & 15) * 1024 + threadIdx.x * 4;
    float4 x = *(const float4*)(ws[m] + off);
    ushort4 h, l;
    h.x = f2bf(x.x); l.x = f2bf(x.x - bf2f(h.x));
    h.y = f2bf(x.y); l.y = f2bf(x.y - bf2f(h.y));
    h.z = f2bf(x.z); l.z = f2bf(x.z - bf2f(h.z));
    h.w = f2bf(x.w); l.w = f2bf(x.w - bf2f(h.w));
    size_t o = (size_t)m * 16384 + off;
    *(ushort4*)(Wh + o) = h;
    *(ushort4*)(Wl + o) = l;
}

// ---------------- MFMA split-bf16 GEMM: Y = X @ W^T + b ----------------
// No LDS. Each block: 4 waves, 256 rows, one output matrix (blockIdx.y).
// Wave w owns cols [32w, 32w+32) as two 16x16 col-tiles; W fragments live in
// VGPRs for the whole block (64 VGPRs), X fragments stream from global.
// A-frag: lane holds Xh[row=m0+(lane&15)][k=quad*8 .. +8) -- 16B contiguous.
// B-frag: lane holds W [n=n0+(lane&15)][k=quad*8 .. +8)  -- W is [out,in] row-major = B^T rows.
// C/D:    lane&15 = col, quad*4+reg = row (m91-verified mapping).

__global__ __launch_bounds__(256) void gemm_mfma_kernel(
    const ushort_t* __restrict__ Xh, const ushort_t* __restrict__ Xl,
    const ushort_t* __restrict__ Wh, const ushort_t* __restrict__ Wl,
    int lw,                                  // weight slot base (0 or 4)
    const float* __restrict__ b0, const float* __restrict__ b1,
    const float* __restrict__ b2, const float* __restrict__ b3,
    float* __restrict__ O0, float* __restrict__ O1,
    float* __restrict__ O2, float* __restrict__ O3) {
    int which = blockIdx.y;
    const ushort_t* wh = Wh + (size_t)(lw + which) * 16384;
    const ushort_t* wl = Wl + (size_t)(lw + which) * 16384;
    const float* bias = (which == 0) ? b0 : (which == 1) ? b1 : (which == 2) ? b2 : b3;
    float*       Osel = (which == 0) ? O0 : (which == 1) ? O1 : (which == 2) ? O2 : O3;

    int w = threadIdx.x >> 6;
    int lane = threadIdx.x & 63;
    int quad = lane >> 4, ln = lane & 15;
    int n0 = w * 32;

    // load weight fragments once (L1/L2-resident, shared by all blocks)
    bf16x8 bh[2][4], bl[2][4];
#pragma unroll
    for (int ct = 0; ct < 2; ++ct)
#pragma unroll
        for (int kc = 0; kc < 4; ++kc) {
            int addr = (n0 + ct * 16 + ln) * 128 + kc * 32 + quad * 8;
            bh[ct][kc] = *(const bf16x8*)(wh + addr);
            bl[ct][kc] = *(const bf16x8*)(wl + addr);
        }
    float bias0 = bias[n0 + ln];
    float bias1 = bias[n0 + 16 + ln];

    int rowBase = blockIdx.x * 256;
    for (int r = 0; r < 16; ++r) {
        int m0 = rowBase + r * 16;
        int rm = min(m0 + ln, Nn - 1);                 // clamp loads; stores guarded
        size_t abase = (size_t)rm * 128 + quad * 8;
        bf16x8 ah[4], al[4];
#pragma unroll
        for (int kc = 0; kc < 4; ++kc) {
            ah[kc] = *(const bf16x8*)(Xh + abase + kc * 32);
            al[kc] = *(const bf16x8*)(Xl + abase + kc * 32);
        }
        f32x4 acc0 = {0.f, 0.f, 0.f, 0.f};
        f32x4 acc1 = {0.f, 0.f, 0.f, 0.f};
#pragma unroll
        for (int kc = 0; kc < 4; ++kc) {
            acc0 = __builtin_amdgcn_mfma_f32_16x16x32_bf16(ah[kc], bh[0][kc], acc0, 0, 0, 0);
            acc1 = __builtin_amdgcn_mfma_f32_16x16x32_bf16(ah[kc], bh[1][kc], acc1, 0, 0, 0);
            acc0 = __builtin_amdgcn_mfma_f32_16x16x32_bf16(ah[kc], bl[0][kc], acc0, 0, 0, 0);
            acc1 = __builtin_amdgcn_mfma_f32_16x16x32_bf16(ah[kc], bl[1][kc], acc1, 0, 0, 0);
            acc0 = __builtin_amdgcn_mfma_f32_16x16x32_bf16(al[kc], bh[0][kc], acc0, 0, 0, 0);
            acc1 = __builtin_amdgcn_mfma_f32_16x16x32_bf16(al[kc], bh[1][kc], acc1, 0, 0, 0);
        }
#pragma unroll
        for (int reg = 0; reg < 4; ++reg) {
            int orow = m0 + quad * 4 + reg;
            if (orow < Nn) {
                size_t ob = (size_t)orow * 128;
                Osel[ob + n0 + ln]      = acc0[reg] + bias0;
                Osel[ob + n0 + 16 + ln] = acc1[reg] + bias1;
            }
        }
    }
}

// ---------------- fused per-node attention (two-pass per chunk) ----------------

constexpr int CHUNK = 128;

__global__ __launch_bounds__(256) void attn_kernel(const float* __restrict__ q,
                                                   const float* __restrict__ k,
                                                   const float* __restrict__ v,
                                                   const float* __restrict__ s,
                                                   const int* __restrict__ offsets,
                                                   const int* __restrict__ sorted_src,
                                                   float* __restrict__ h) {
    __shared__ float astash[4][CHUNK];
    int wslot = threadIdx.x >> 6;
    int wid = blockIdx.x * 4 + wslot;
    if (wid >= Nn) return;
    int lane = threadIdx.x & 63;
    int gid = lane >> 5;         // group 0/1 (edge parity)
    int gl = lane & 31;          // lane within group, holds 4 dims
    const float4 qv = ((const float4*)(q + (size_t)wid * Dd))[gl];
    int beg = offsets[wid], end = offsets[wid + 1];

    float m = -INFINITY, l = 0.f;
    float4 acc = make_float4(0.f, 0.f, 0.f, 0.f);

    for (int cbeg = beg; cbeg < end; cbeg += CHUNK) {
        int cend = min(cbeg + CHUNK, end);
        float cm = -INFINITY;
        for (int e = cbeg + gid; e < cend; e += 2) {
            int sidx = sorted_src[e];
            float4 kv = ((const float4*)(k + (size_t)sidx * Dd))[gl];
            float part = qv.x * kv.x + qv.y * kv.y + qv.z * kv.z + qv.w * kv.w;
#pragma unroll
            for (int off = 16; off > 0; off >>= 1) part += __shfl_xor(part, off, 64);
            float a = part * SCALE;
            if (gl == 0) astash[wslot][e - cbeg] = a;
            cm = fmaxf(cm, a);
        }
        cm = fmaxf(cm, __shfl_xor(cm, 32, 64));
        float mn = fmaxf(m, cm);
        float sc = (m > -INFINITY) ? __expf(m - mn) : 0.f;
        l *= sc; acc.x *= sc; acc.y *= sc; acc.z *= sc; acc.w *= sc;
        for (int e = cbeg + gid; e < cend; e += 2) {
            float w = __expf(astash[wslot][e - cbeg] - mn);
            int sidx = sorted_src[e];
            float4 vv = ((const float4*)(v + (size_t)sidx * Dd))[gl];
            l += w;
            acc.x += w * vv.x; acc.y += w * vv.y;
            acc.z += w * vv.z; acc.w += w * vv.w;
        }
        m = mn;
    }

    l += __shfl_xor(l, 32, 64);
    acc.x += __shfl_xor(acc.x, 32, 64);
    acc.y += __shfl_xor(acc.y, 32, 64);
    acc.z += __shfl_xor(acc.z, 32, 64);
    acc.w += __shfl_xor(acc.w, 32, 64);

    if (gid == 0) {
        float inv = (l > 0.f) ? (1.0f / l) : 0.f;   // deg==0 -> pure skip
        float4 sk = ((const float4*)(s + (size_t)wid * Dd))[gl];
        float4 o;
        o.x = fmaxf(acc.x * inv + sk.x, 0.f);       // + skip, ReLU
        o.y = fmaxf(acc.y * inv + sk.y, 0.f);
        o.z = fmaxf(acc.z * inv + sk.z, 0.f);
        o.w = fmaxf(acc.w * inv + sk.w, 0.f);
        ((float4*)(h + (size_t)wid * Dd))[gl] = o;
    }
}

// ---------------- pooling + classifier ----------------

__global__ __launch_bounds__(256) void bound_kernel(const int* __restrict__ batch,
                                                    int* __restrict__ startg,
                                                    int* __restrict__ endg) {
    int n = blockIdx.x * 256 + threadIdx.x;
    if (n >= Nn) return;
    int g = batch[n];
    if (n == Nn - 1 || batch[n + 1] != g) endg[g] = n + 1;
    if (n == 0 || batch[n - 1] != g) startg[g] = n;
}

__global__ __launch_bounds__(128) void pool_kernel(const float* __restrict__ h,
                                                   const int* __restrict__ batch,
                                                   float* __restrict__ pooled) {
    int c = threadIdx.x;            // 0..127 (column)
    int n0 = blockIdx.x * 128;
    int nend = min(n0 + 128, Nn);
    int curg = batch[n0];           // batch is sorted -> few segments per block
    float sum = 0.f;
    for (int n = n0; n < nend; ++n) {
        int g = batch[n];
        if (g != curg) {
            atomicAdd(&pooled[curg * Dd + c], sum);
            sum = 0.f;
            curg = g;
        }
        sum += h[(size_t)n * Dd + c];
    }
    atomicAdd(&pooled[curg * Dd + c], sum);
}

__global__ __launch_bounds__(64) void mlp_kernel(const float* __restrict__ pooled,
                                                 const int* __restrict__ startg,
                                                 const int* __restrict__ endg,
                                                 const float* __restrict__ Wc1,
                                                 const float* __restrict__ bc1,
                                                 const float* __restrict__ Wc2,
                                                 const float* __restrict__ bc2,
                                                 float* __restrict__ out) {
    __shared__ float pm[128];
    __shared__ float hid[64];
    int g = blockIdx.x, t = threadIdx.x;   // 64 threads
    float cnt = fmaxf((float)(endg[g] - startg[g]), 1.0f);
    float invc = 1.0f / cnt;
    pm[t]      = pooled[g * 128 + t] * invc;
    pm[t + 64] = pooled[g * 128 + 64 + t] * invc;
    __syncthreads();
    float acc = bc1[t];
    for (int i = 0; i < 128; ++i) acc += pm[i] * Wc1[t * 128 + i];
    hid[t] = fmaxf(acc, 0.f);
    __syncthreads();
    if (t < 2) {
        float a = bc2[t];
        for (int i = 0; i < 64; ++i) a += hid[i] * Wc2[t * 64 + i];
        out[g * 2 + t] = a;
    }
}

// ---------------- launch ----------------

extern "C" void kernel_launch(void* const* d_in, const int* in_sizes, int n_in,
                              void* d_out, int out_size, void* d_ws, size_t ws_size,
                              hipStream_t stream) {
    const float* x   = (const float*)d_in[0];
    const int*   ei  = (const int*)d_in[1];
    const int* batch = (const int*)d_in[2];
    const float* W[2][4];
    const float* B[2][4];
    for (int l = 0; l < 2; ++l) {
        for (int j = 0; j < 4; ++j) W[l][j] = (const float*)d_in[3 + l * 8 + j];
        for (int j = 0; j < 4; ++j) B[l][j] = (const float*)d_in[3 + l * 8 + 4 + j];
    }
    const float* Wc1 = (const float*)d_in[19];
    const float* bc1 = (const float*)d_in[20];
    const float* Wc2 = (const float*)d_in[21];
    const float* bc2 = (const float*)d_in[22];
    float* out = (float*)d_out;

    const int* src = ei;        // edge_index[0]
    const int* dst = ei + Ee;   // edge_index[1]

    char* p = (char*)d_ws;
    auto alloc = [&](size_t bytes) {
        void* r = (void*)p;
        p += (bytes + 255) & ~(size_t)255;
        return r;
    };
    float* q  = (float*)alloc((size_t)Nn * Dd * 4);
    float* kk = (float*)alloc((size_t)Nn * Dd * 4);
    float* vv = (float*)alloc((size_t)Nn * Dd * 4);
    float* ss = (float*)alloc((size_t)Nn * Dd * 4);
    float* h  = (float*)alloc((size_t)Nn * Dd * 4);
    ushort_t* Xh = (ushort_t*)alloc((size_t)Nn * Dd * 2);
    ushort_t* Xl = (ushort_t*)alloc((size_t)Nn * Dd * 2);
    ushort_t* Wh = (ushort_t*)alloc((size_t)8 * 16384 * 2);
    ushort_t* Wl = (ushort_t*)alloc((size_t)8 * 16384 * 2);
    char* zbase = p;  // region zeroed each launch
    int*   counts = (int*)alloc(Nn * 4);
    int*   startg = (int*)alloc(Gg * 4);
    int*   endg   = (int*)alloc(Gg * 4);
    float* pooled = (float*)alloc(Gg * Dd * 4);
    size_t zbytes = (size_t)(p - zbase);
    int* offsets    = (int*)alloc((size_t)(Nn + 1) * 4);
    int* cursor     = (int*)alloc(Nn * 4);
    int* blockSums  = (int*)alloc(256 * 4);
    int* sorted_src = (int*)alloc((size_t)Ee * 4);

    hipMemsetAsync(zbase, 0, zbytes, stream);

    constexpr int NB = (Nn + 255) / 256;  // 196 scan blocks
    hist_kernel<<<(Ee + 255) / 256, 256, 0, stream>>>(dst, counts);
    scan1_kernel<<<NB, 256, 0, stream>>>(counts, offsets, blockSums);
    scan2_kernel<<<1, 256, 0, stream>>>(blockSums, NB);
    scan3_kernel<<<NB, 256, 0, stream>>>(offsets, blockSums, cursor);
    scatter_kernel<<<(Ee + 255) / 256, 256, 0, stream>>>(src, dst, cursor, sorted_src);

    convw_kernel<<<128, 256, 0, stream>>>(W[0][0], W[0][1], W[0][2], W[0][3],
                                          W[1][0], W[1][1], W[1][2], W[1][3], Wh, Wl);

    constexpr int N4 = Nn * Dd / 4;       // 1.6M float4s
    dim3 ggrid((Nn + 255) / 256, 4);      // 196 row-groups x 4 output matrices

    // layer 0
    convx_kernel<<<(N4 + 255) / 256, 256, 0, stream>>>(x, Xh, Xl, N4);
    gemm_mfma_kernel<<<ggrid, 256, 0, stream>>>(Xh, Xl, Wh, Wl, 0,
                                                B[0][0], B[0][1], B[0][2], B[0][3],
                                                q, kk, vv, ss);
    attn_kernel<<<(Nn + 3) / 4, 256, 0, stream>>>(q, kk, vv, ss, offsets, sorted_src, h);
    // layer 1
    convx_kernel<<<(N4 + 255) / 256, 256, 0, stream>>>(h, Xh, Xl, N4);
    gemm_mfma_kernel<<<ggrid, 256, 0, stream>>>(Xh, Xl, Wh, Wl, 4,
                                                B[1][0], B[1][1], B[1][2], B[1][3],
                                                q, kk, vv, ss);
    attn_kernel<<<(Nn + 3) / 4, 256, 0, stream>>>(q, kk, vv, ss, offsets, sorted_src, h);

    bound_kernel<<<(Nn + 255) / 256, 256, 0, stream>>>(batch, startg, endg);
    pool_kernel<<<(Nn + 127) / 128, 128, 0, stream>>>(h, batch, pooled);
    mlp_kernel<<<Gg, 64, 0, stream>>>(pooled, startg, endg, Wc1, bc1, Wc2, bc2, out);
}

// Round 4
// 550.749 us; speedup vs baseline: 1.5284x; 1.1885x over previous
//
#include <hip/hip_runtime.h>
#include <math.h>

typedef __bf16 bf16x8 __attribute__((ext_vector_type(8)));
typedef float  f32x4  __attribute__((ext_vector_type(4)));
typedef unsigned short ushort_t;
typedef unsigned short ushort8 __attribute__((ext_vector_type(8)));

// Problem constants (fixed by the reference).
constexpr int Nn = 50000;   // nodes
constexpr int Ee = 800000;  // edges
constexpr int Dd = 128;     // feature dim
constexpr int Gg = 64;      // graphs
constexpr float SCALE = 0.08838834764831845f; // 1/sqrt(128)

__device__ inline ushort_t f2bf(float f) {
    unsigned u = __float_as_uint(f);
    unsigned r = (u + 0x7FFF + ((u >> 16) & 1)) >> 16;   // RNE truncate to bf16
    return (ushort_t)r;
}
__device__ inline float bf2f(ushort_t b) { return __uint_as_float(((unsigned)b) << 16); }

// ---------------- CSR build (sort edges by dst) ----------------

__global__ __launch_bounds__(256) void hist_kernel(const int* __restrict__ dst,
                                                   int* __restrict__ counts) {
    int e = blockIdx.x * 256 + threadIdx.x;
    if (e < Ee) atomicAdd(&counts[dst[e]], 1);
}

__global__ __launch_bounds__(256) void scan1_kernel(const int* __restrict__ counts,
                                                    int* __restrict__ offsets,
                                                    int* __restrict__ blockSums) {
    __shared__ int sh[256];
    int i = blockIdx.x * 256 + threadIdx.x;
    int v = (i < Nn) ? counts[i] : 0;
    sh[threadIdx.x] = v;
    __syncthreads();
    for (int off = 1; off < 256; off <<= 1) {
        int t = (threadIdx.x >= off) ? sh[threadIdx.x - off] : 0;
        __syncthreads();
        sh[threadIdx.x] += t;
        __syncthreads();
    }
    if (i < Nn) offsets[i] = sh[threadIdx.x] - v;   // exclusive within block
    if (threadIdx.x == 255) blockSums[blockIdx.x] = sh[255];
}

__global__ __launch_bounds__(256) void scan2_kernel(int* __restrict__ blockSums, int nb) {
    __shared__ int sh[256];
    int t = threadIdx.x;
    int v = (t < nb) ? blockSums[t] : 0;
    sh[t] = v;
    __syncthreads();
    for (int off = 1; off < 256; off <<= 1) {
        int u = (t >= off) ? sh[t - off] : 0;
        __syncthreads();
        sh[t] += u;
        __syncthreads();
    }
    if (t < nb) blockSums[t] = sh[t] - v;           // exclusive across blocks
}

__global__ __launch_bounds__(256) void scan3_kernel(int* __restrict__ offsets,
                                                    const int* __restrict__ blockSums,
                                                    int* __restrict__ cursor) {
    int i = blockIdx.x * 256 + threadIdx.x;
    if (i < Nn) {
        int o = offsets[i] + blockSums[blockIdx.x];
        offsets[i] = o;
        cursor[i] = o;
    }
    if (i == 0) offsets[Nn] = Ee;
}

__global__ __launch_bounds__(256) void scatter_kernel(const int* __restrict__ src,
                                                      const int* __restrict__ dst,
                                                      int* __restrict__ cursor,
                                                      int* __restrict__ sorted_src) {
    int e = blockIdx.x * 256 + threadIdx.x;
    if (e < Ee) {
        int d = dst[e];
        int pos = atomicAdd(&cursor[d], 1);
        sorted_src[pos] = src[e];
    }
}

// ---------------- split-bf16 conversion ----------------

__global__ __launch_bounds__(256) void convx_kernel(const float* __restrict__ X,
                                                    ushort_t* __restrict__ Xh,
                                                    ushort_t* __restrict__ Xl,
                                                    int n4) {
    int i = blockIdx.x * 256 + threadIdx.x;
    if (i >= n4) return;
    float4 x = ((const float4*)X)[i];
    ushort4 h, l;
    h.x = f2bf(x.x); l.x = f2bf(x.x - bf2f(h.x));
    h.y = f2bf(x.y); l.y = f2bf(x.y - bf2f(h.y));
    h.z = f2bf(x.z); l.z = f2bf(x.z - bf2f(h.z));
    h.w = f2bf(x.w); l.w = f2bf(x.w - bf2f(h.w));
    ((ushort4*)Xh)[i] = h;
    ((ushort4*)Xl)[i] = l;
}

__global__ __launch_bounds__(256) void convw_kernel(
    const float* w0, const float* w1, const float* w2, const float* w3,
    const float* w4, const float* w5, const float* w6, const float* w7,
    ushort_t* __restrict__ Wh, ushort_t* __restrict__ Wl) {
    const float* ws[8] = {w0, w1, w2, w3, w4, w5, w6, w7};
    int m = blockIdx.x >> 4;                       // 16 blocks per 16384-elem matrix
    int off = (blockIdx.x & 15) * 1024 + threadIdx.x * 4;
    float4 x = *(const float4*)(ws[m] + off);
    ushort4 h, l;
    h.x = f2bf(x.x); l.x = f2bf(x.x - bf2f(h.x));
    h.y = f2bf(x.y); l.y = f2bf(x.y - bf2f(h.y));
    h.z = f2bf(x.z); l.z = f2bf(x.z - bf2f(h.z));
    h.w = f2bf(x.w); l.w = f2bf(x.w - bf2f(h.w));
    size_t o = (size_t)m * 16384 + off;
    *(ushort4*)(Wh + o) = h;
    *(ushort4*)(Wl + o) = l;
}

// ---------------- MFMA split-bf16 GEMM: Y = X @ W^T + b ----------------
// q,s outputs in fp32; k,v outputs in bf16 (bfmask bit per matrix) to halve
// the attention gather traffic.

__global__ __launch_bounds__(256) void gemm_mfma_kernel(
    const ushort_t* __restrict__ Xh, const ushort_t* __restrict__ Xl,
    const ushort_t* __restrict__ Wh, const ushort_t* __restrict__ Wl,
    int lw, unsigned bfmask,
    const float* __restrict__ b0, const float* __restrict__ b1,
    const float* __restrict__ b2, const float* __restrict__ b3,
    void* __restrict__ O0, void* __restrict__ O1,
    void* __restrict__ O2, void* __restrict__ O3) {
    int which = blockIdx.y;
    const ushort_t* wh = Wh + (size_t)(lw + which) * 16384;
    const ushort_t* wl = Wl + (size_t)(lw + which) * 16384;
    const float* bias = (which == 0) ? b0 : (which == 1) ? b1 : (which == 2) ? b2 : b3;
    void*        Osel = (which == 0) ? O0 : (which == 1) ? O1 : (which == 2) ? O2 : O3;
    bool obf = (bfmask >> which) & 1;
    float*    Of = (float*)Osel;
    ushort_t* Ob = (ushort_t*)Osel;

    int w = threadIdx.x >> 6;
    int lane = threadIdx.x & 63;
    int quad = lane >> 4, ln = lane & 15;
    int n0 = w * 32;

    bf16x8 bh[2][4], bl[2][4];
#pragma unroll
    for (int ct = 0; ct < 2; ++ct)
#pragma unroll
        for (int kc = 0; kc < 4; ++kc) {
            int addr = (n0 + ct * 16 + ln) * 128 + kc * 32 + quad * 8;
            bh[ct][kc] = *(const bf16x8*)(wh + addr);
            bl[ct][kc] = *(const bf16x8*)(wl + addr);
        }
    float bias0 = bias[n0 + ln];
    float bias1 = bias[n0 + 16 + ln];

    int rowBase = blockIdx.x * 256;
    for (int r = 0; r < 16; ++r) {
        int m0 = rowBase + r * 16;
        int rm = min(m0 + ln, Nn - 1);                 // clamp loads; stores guarded
        size_t abase = (size_t)rm * 128 + quad * 8;
        bf16x8 ah[4], al[4];
#pragma unroll
        for (int kc = 0; kc < 4; ++kc) {
            ah[kc] = *(const bf16x8*)(Xh + abase + kc * 32);
            al[kc] = *(const bf16x8*)(Xl + abase + kc * 32);
        }
        f32x4 acc0 = {0.f, 0.f, 0.f, 0.f};
        f32x4 acc1 = {0.f, 0.f, 0.f, 0.f};
#pragma unroll
        for (int kc = 0; kc < 4; ++kc) {
            acc0 = __builtin_amdgcn_mfma_f32_16x16x32_bf16(ah[kc], bh[0][kc], acc0, 0, 0, 0);
            acc1 = __builtin_amdgcn_mfma_f32_16x16x32_bf16(ah[kc], bh[1][kc], acc1, 0, 0, 0);
            acc0 = __builtin_amdgcn_mfma_f32_16x16x32_bf16(ah[kc], bl[0][kc], acc0, 0, 0, 0);
            acc1 = __builtin_amdgcn_mfma_f32_16x16x32_bf16(ah[kc], bl[1][kc], acc1, 0, 0, 0);
            acc0 = __builtin_amdgcn_mfma_f32_16x16x32_bf16(al[kc], bh[0][kc], acc0, 0, 0, 0);
            acc1 = __builtin_amdgcn_mfma_f32_16x16x32_bf16(al[kc], bh[1][kc], acc1, 0, 0, 0);
        }
#pragma unroll
        for (int reg = 0; reg < 4; ++reg) {
            int orow = m0 + quad * 4 + reg;
            if (orow < Nn) {
                size_t ob = (size_t)orow * 128;
                float o0 = acc0[reg] + bias0;
                float o1 = acc1[reg] + bias1;
                if (obf) {
                    Ob[ob + n0 + ln]      = f2bf(o0);
                    Ob[ob + n0 + 16 + ln] = f2bf(o1);
                } else {
                    Of[ob + n0 + ln]      = o0;
                    Of[ob + n0 + 16 + ln] = o1;
                }
            }
        }
    }
}

// ---------------- fused per-node attention ----------------
// One 64-lane wave per node: 4 groups x 16 lanes. Lane gl holds dims
// [gl*8, gl*8+8); group g processes edges e ≡ g (mod 4). k/v gathers are
// bf16 (16B/lane), fp32 math. Two-pass per chunk with LDS score stash.

constexpr int CHUNK = 128;

__global__ __launch_bounds__(256) void attn_kernel(const float* __restrict__ q,
                                                   const ushort_t* __restrict__ k,
                                                   const ushort_t* __restrict__ v,
                                                   const float* __restrict__ s,
                                                   const int* __restrict__ offsets,
                                                   const int* __restrict__ sorted_src,
                                                   float* __restrict__ h) {
    __shared__ float astash[4][CHUNK];
    int wslot = threadIdx.x >> 6;
    int wid = blockIdx.x * 4 + wslot;
    if (wid >= Nn) return;
    int lane = threadIdx.x & 63;
    int g = lane >> 4;           // edge parity group 0..3
    int gl = lane & 15;          // dim chunk within row
    const float4* qrow = (const float4*)(q + (size_t)wid * Dd);
    float4 q0 = qrow[gl * 2];
    float4 q1 = qrow[gl * 2 + 1];
    int beg = offsets[wid], end = offsets[wid + 1];

    float m = -INFINITY, l = 0.f;
    float acc[8];
#pragma unroll
    for (int j = 0; j < 8; ++j) acc[j] = 0.f;

    for (int cbeg = beg; cbeg < end; cbeg += CHUNK) {
        int cend = min(cbeg + CHUNK, end);
        float cm = -INFINITY;
        // pass 1: scores
        for (int e = cbeg + g; e < cend; e += 4) {
            int sidx = sorted_src[e];
            ushort8 kv = *(const ushort8*)(k + (size_t)sidx * Dd + gl * 8);
            float part = q0.x * bf2f(kv[0]) + q0.y * bf2f(kv[1]) +
                         q0.z * bf2f(kv[2]) + q0.w * bf2f(kv[3]) +
                         q1.x * bf2f(kv[4]) + q1.y * bf2f(kv[5]) +
                         q1.z * bf2f(kv[6]) + q1.w * bf2f(kv[7]);
#pragma unroll
            for (int off = 8; off > 0; off >>= 1) part += __shfl_xor(part, off, 64);
            float a = part * SCALE;
            if (gl == 0) astash[wslot][e - cbeg] = a;
            cm = fmaxf(cm, a);
        }
        cm = fmaxf(cm, __shfl_xor(cm, 16, 64));
        cm = fmaxf(cm, __shfl_xor(cm, 32, 64));
        float mn = fmaxf(m, cm);
        float sc = (m > -INFINITY) ? __expf(m - mn) : 0.f;
        l *= sc;
#pragma unroll
        for (int j = 0; j < 8; ++j) acc[j] *= sc;
        // pass 2: weights + V accumulation
        for (int e = cbeg + g; e < cend; e += 4) {
            float w = __expf(astash[wslot][e - cbeg] - mn);
            int sidx = sorted_src[e];
            ushort8 vv = *(const ushort8*)(v + (size_t)sidx * Dd + gl * 8);
            l += w;
#pragma unroll
            for (int j = 0; j < 8; ++j) acc[j] += w * bf2f(vv[j]);
        }
        m = mn;
    }

    // combine the 4 groups' partials (dims align across groups at same gl)
    l += __shfl_xor(l, 16, 64);
    l += __shfl_xor(l, 32, 64);
#pragma unroll
    for (int j = 0; j < 8; ++j) {
        acc[j] += __shfl_xor(acc[j], 16, 64);
        acc[j] += __shfl_xor(acc[j], 32, 64);
    }

    if (g == 0) {
        float inv = (l > 0.f) ? (1.0f / l) : 0.f;   // deg==0 -> pure skip
        const float4* srow = (const float4*)(s + (size_t)wid * Dd);
        float4 sk0 = srow[gl * 2];
        float4 sk1 = srow[gl * 2 + 1];
        float4 o0, o1;
        o0.x = fmaxf(acc[0] * inv + sk0.x, 0.f);
        o0.y = fmaxf(acc[1] * inv + sk0.y, 0.f);
        o0.z = fmaxf(acc[2] * inv + sk0.z, 0.f);
        o0.w = fmaxf(acc[3] * inv + sk0.w, 0.f);
        o1.x = fmaxf(acc[4] * inv + sk1.x, 0.f);
        o1.y = fmaxf(acc[5] * inv + sk1.y, 0.f);
        o1.z = fmaxf(acc[6] * inv + sk1.z, 0.f);
        o1.w = fmaxf(acc[7] * inv + sk1.w, 0.f);
        float4* hrow = (float4*)(h + (size_t)wid * Dd);
        hrow[gl * 2]     = o0;
        hrow[gl * 2 + 1] = o1;
    }
}

// ---------------- pooling + classifier ----------------

__global__ __launch_bounds__(256) void bound_kernel(const int* __restrict__ batch,
                                                    int* __restrict__ startg,
                                                    int* __restrict__ endg) {
    int n = blockIdx.x * 256 + threadIdx.x;
    if (n >= Nn) return;
    int g = batch[n];
    if (n == Nn - 1 || batch[n + 1] != g) endg[g] = n + 1;
    if (n == 0 || batch[n - 1] != g) startg[g] = n;
}

__global__ __launch_bounds__(128) void pool_kernel(const float* __restrict__ h,
                                                   const int* __restrict__ batch,
                                                   float* __restrict__ pooled) {
    int c = threadIdx.x;            // 0..127 (column)
    int n0 = blockIdx.x * 128;
    int nend = min(n0 + 128, Nn);
    int curg = batch[n0];           // batch is sorted -> few segments per block
    float sum = 0.f;
    for (int n = n0; n < nend; ++n) {
        int g = batch[n];
        if (g != curg) {
            atomicAdd(&pooled[curg * Dd + c], sum);
            sum = 0.f;
            curg = g;
        }
        sum += h[(size_t)n * Dd + c];
    }
    atomicAdd(&pooled[curg * Dd + c], sum);
}

__global__ __launch_bounds__(64) void mlp_kernel(const float* __restrict__ pooled,
                                                 const int* __restrict__ startg,
                                                 const int* __restrict__ endg,
                                                 const float* __restrict__ Wc1,
                                                 const float* __restrict__ bc1,
                                                 const float* __restrict__ Wc2,
                                                 const float* __restrict__ bc2,
                                                 float* __restrict__ out) {
    __shared__ float pm[128];
    __shared__ float hid[64];
    int g = blockIdx.x, t = threadIdx.x;   // 64 threads
    float cnt = fmaxf((float)(endg[g] - startg[g]), 1.0f);
    float invc = 1.0f / cnt;
    pm[t]      = pooled[g * 128 + t] * invc;
    pm[t + 64] = pooled[g * 128 + 64 + t] * invc;
    __syncthreads();
    float acc = bc1[t];
    for (int i = 0; i < 128; ++i) acc += pm[i] * Wc1[t * 128 + i];
    hid[t] = fmaxf(acc, 0.f);
    __syncthreads();
    if (t < 2) {
        float a = bc2[t];
        for (int i = 0; i < 64; ++i) a += hid[i] * Wc2[t * 64 + i];
        out[g * 2 + t] = a;
    }
}

// ---------------- launch ----------------

extern "C" void kernel_launch(void* const* d_in, const int* in_sizes, int n_in,
                              void* d_out, int out_size, void* d_ws, size_t ws_size,
                              hipStream_t stream) {
    const float* x   = (const float*)d_in[0];
    const int*   ei  = (const int*)d_in[1];
    const int* batch = (const int*)d_in[2];
    const float* W[2][4];
    const float* B[2][4];
    for (int l = 0; l < 2; ++l) {
        for (int j = 0; j < 4; ++j) W[l][j] = (const float*)d_in[3 + l * 8 + j];
        for (int j = 0; j < 4; ++j) B[l][j] = (const float*)d_in[3 + l * 8 + 4 + j];
    }
    const float* Wc1 = (const float*)d_in[19];
    const float* bc1 = (const float*)d_in[20];
    const float* Wc2 = (const float*)d_in[21];
    const float* bc2 = (const float*)d_in[22];
    float* out = (float*)d_out;

    const int* src = ei;        // edge_index[0]
    const int* dst = ei + Ee;   // edge_index[1]

    char* p = (char*)d_ws;
    auto alloc = [&](size_t bytes) {
        void* r = (void*)p;
        p += (bytes + 255) & ~(size_t)255;
        return r;
    };
    float*    q  = (float*)alloc((size_t)Nn * Dd * 4);
    ushort_t* kk = (ushort_t*)alloc((size_t)Nn * Dd * 2);   // bf16
    ushort_t* vv = (ushort_t*)alloc((size_t)Nn * Dd * 2);   // bf16
    float*    ss = (float*)alloc((size_t)Nn * Dd * 4);
    float*    h  = (float*)alloc((size_t)Nn * Dd * 4);
    ushort_t* Xh = (ushort_t*)alloc((size_t)Nn * Dd * 2);
    ushort_t* Xl = (ushort_t*)alloc((size_t)Nn * Dd * 2);
    ushort_t* Wh = (ushort_t*)alloc((size_t)8 * 16384 * 2);
    ushort_t* Wl = (ushort_t*)alloc((size_t)8 * 16384 * 2);
    char* zbase = p;  // region zeroed each launch
    int*   counts = (int*)alloc(Nn * 4);
    int*   startg = (int*)alloc(Gg * 4);
    int*   endg   = (int*)alloc(Gg * 4);
    float* pooled = (float*)alloc(Gg * Dd * 4);
    size_t zbytes = (size_t)(p - zbase);
    int* offsets    = (int*)alloc((size_t)(Nn + 1) * 4);
    int* cursor     = (int*)alloc(Nn * 4);
    int* blockSums  = (int*)alloc(256 * 4);
    int* sorted_src = (int*)alloc((size_t)Ee * 4);

    hipMemsetAsync(zbase, 0, zbytes, stream);

    constexpr int NB = (Nn + 255) / 256;  // 196 scan blocks
    hist_kernel<<<(Ee + 255) / 256, 256, 0, stream>>>(dst, counts);
    scan1_kernel<<<NB, 256, 0, stream>>>(counts, offsets, blockSums);
    scan2_kernel<<<1, 256, 0, stream>>>(blockSums, NB);
    scan3_kernel<<<NB, 256, 0, stream>>>(offsets, blockSums, cursor);
    scatter_kernel<<<(Ee + 255) / 256, 256, 0, stream>>>(src, dst, cursor, sorted_src);

    convw_kernel<<<128, 256, 0, stream>>>(W[0][0], W[0][1], W[0][2], W[0][3],
                                          W[1][0], W[1][1], W[1][2], W[1][3], Wh, Wl);

    constexpr int N4 = Nn * Dd / 4;
    dim3 ggrid((Nn + 255) / 256, 4);
    constexpr unsigned BFMASK = 0b0110;   // k (1) and v (2) in bf16

    // layer 0
    convx_kernel<<<(N4 + 255) / 256, 256, 0, stream>>>(x, Xh, Xl, N4);
    gemm_mfma_kernel<<<ggrid, 256, 0, stream>>>(Xh, Xl, Wh, Wl, 0, BFMASK,
                                                B[0][0], B[0][1], B[0][2], B[0][3],
                                                q, kk, vv, ss);
    attn_kernel<<<(Nn + 3) / 4, 256, 0, stream>>>(q, kk, vv, ss, offsets, sorted_src, h);
    // layer 1
    convx_kernel<<<(N4 + 255) / 256, 256, 0, stream>>>(h, Xh, Xl, N4);
    gemm_mfma_kernel<<<ggrid, 256, 0, stream>>>(Xh, Xl, Wh, Wl, 4, BFMASK,
                                                B[1][0], B[1][1], B[1][2], B[1][3],
                                                q, kk, vv, ss);
    attn_kernel<<<(Nn + 3) / 4, 256, 0, stream>>>(q, kk, vv, ss, offsets, sorted_src, h);

    bound_kernel<<<(Nn + 255) / 256, 256, 0, stream>>>(batch, startg, endg);
    pool_kernel<<<(Nn + 127) / 128, 128, 0, stream>>>(h, batch, pooled);
    mlp_kernel<<<Gg, 64, 0, stream>>>(pooled, startg, endg, Wc1, bc1, Wc2, bc2, out);
}

// Round 6
// 538.512 us; speedup vs baseline: 1.5631x; 1.0227x over previous
//
#include <hip/hip_runtime.h>
#include <math.h>

typedef __bf16 bf16x8 __attribute__((ext_vector_type(8)));
typedef float  f32x4  __attribute__((ext_vector_type(4)));
typedef unsigned short ushort_t;
typedef unsigned short ushort8 __attribute__((ext_vector_type(8)));

// Problem constants (fixed by the reference).
constexpr int Nn = 50000;   // nodes
constexpr int Ee = 800000;  // edges
constexpr int Dd = 128;     // feature dim
constexpr int Gg = 64;      // graphs
constexpr float SCALE = 0.08838834764831845f; // 1/sqrt(128)

__device__ inline ushort_t f2bf(float f) {
    unsigned u = __float_as_uint(f);
    unsigned r = (u + 0x7FFF + ((u >> 16) & 1)) >> 16;   // RNE truncate to bf16
    return (ushort_t)r;
}
__device__ inline float bf2f(ushort_t b) { return __uint_as_float(((unsigned)b) << 16); }

// ---------------- CSR build (sort edges by dst) ----------------

__global__ __launch_bounds__(256) void hist_kernel(const int* __restrict__ dst,
                                                   int* __restrict__ counts) {
    int e = blockIdx.x * 256 + threadIdx.x;
    if (e < Ee) atomicAdd(&counts[dst[e]], 1);
}

__global__ __launch_bounds__(256) void scan1_kernel(const int* __restrict__ counts,
                                                    int* __restrict__ offsets,
                                                    int* __restrict__ blockSums) {
    __shared__ int sh[256];
    int i = blockIdx.x * 256 + threadIdx.x;
    int v = (i < Nn) ? counts[i] : 0;
    sh[threadIdx.x] = v;
    __syncthreads();
    for (int off = 1; off < 256; off <<= 1) {
        int t = (threadIdx.x >= off) ? sh[threadIdx.x - off] : 0;
        __syncthreads();
        sh[threadIdx.x] += t;
        __syncthreads();
    }
    if (i < Nn) offsets[i] = sh[threadIdx.x] - v;   // exclusive within block
    if (threadIdx.x == 255) blockSums[blockIdx.x] = sh[255];
}

__global__ __launch_bounds__(256) void scan2_kernel(int* __restrict__ blockSums, int nb) {
    __shared__ int sh[256];
    int t = threadIdx.x;
    int v = (t < nb) ? blockSums[t] : 0;
    sh[t] = v;
    __syncthreads();
    for (int off = 1; off < 256; off <<= 1) {
        int u = (t >= off) ? sh[t - off] : 0;
        __syncthreads();
        sh[t] += u;
        __syncthreads();
    }
    if (t < nb) blockSums[t] = sh[t] - v;           // exclusive across blocks
}

__global__ __launch_bounds__(256) void scan3_kernel(int* __restrict__ offsets,
                                                    const int* __restrict__ blockSums,
                                                    int* __restrict__ cursor) {
    int i = blockIdx.x * 256 + threadIdx.x;
    if (i < Nn) {
        int o = offsets[i] + blockSums[blockIdx.x];
        offsets[i] = o;
        cursor[i] = o;
    }
    if (i == 0) offsets[Nn] = Ee;
}

__global__ __launch_bounds__(256) void scatter_kernel(const int* __restrict__ src,
                                                      const int* __restrict__ dst,
                                                      int* __restrict__ cursor,
                                                      int* __restrict__ sorted_src) {
    int e = blockIdx.x * 256 + threadIdx.x;
    if (e < Ee) {
        int d = dst[e];
        int pos = atomicAdd(&cursor[d], 1);
        sorted_src[pos] = src[e];
    }
}

// ---------------- split-bf16 conversion ----------------

__global__ __launch_bounds__(256) void convx_kernel(const float* __restrict__ X,
                                                    ushort_t* __restrict__ Xh,
                                                    ushort_t* __restrict__ Xl,
                                                    int n4) {
    int i = blockIdx.x * 256 + threadIdx.x;
    if (i >= n4) return;
    float4 x = ((const float4*)X)[i];
    ushort4 h, l;
    h.x = f2bf(x.x); l.x = f2bf(x.x - bf2f(h.x));
    h.y = f2bf(x.y); l.y = f2bf(x.y - bf2f(h.y));
    h.z = f2bf(x.z); l.z = f2bf(x.z - bf2f(h.z));
    h.w = f2bf(x.w); l.w = f2bf(x.w - bf2f(h.w));
    ((ushort4*)Xh)[i] = h;
    ((ushort4*)Xl)[i] = l;
}

__global__ __launch_bounds__(256) void convw_kernel(
    const float* w0, const float* w1, const float* w2, const float* w3,
    const float* w4, const float* w5, const float* w6, const float* w7,
    ushort_t* __restrict__ Wh, ushort_t* __restrict__ Wl) {
    const float* ws[8] = {w0, w1, w2, w3, w4, w5, w6, w7};
    int m = blockIdx.x >> 4;                       // 16 blocks per 16384-elem matrix
    int off = (blockIdx.x & 15) * 1024 + threadIdx.x * 4;
    float4 x = *(const float4*)(ws[m] + off);
    ushort4 h, l;
    h.x = f2bf(x.x); l.x = f2bf(x.x - bf2f(h.x));
    h.y = f2bf(x.y); l.y = f2bf(x.y - bf2f(h.y));
    h.z = f2bf(x.z); l.z = f2bf(x.z - bf2f(h.z));
    h.w = f2bf(x.w); l.w = f2bf(x.w - bf2f(h.w));
    size_t o = (size_t)m * 16384 + off;
    *(ushort4*)(Wh + o) = h;
    *(ushort4*)(Wl + o) = l;
}

// ---------------- MFMA split-bf16 GEMM: Y = X @ W^T + b ----------------
// Software-pipelined: A-fragments double-buffered (prefetch row r+1 during
// MFMAs of row r); 4 independent accumulator chains (2 col-tiles x 2 k-halves)
// so each chain is only 6 MFMAs deep. q,s out fp32; k,v out bf16 (bfmask).

__global__ __launch_bounds__(256) void gemm_mfma_kernel(
    const ushort_t* __restrict__ Xh, const ushort_t* __restrict__ Xl,
    const ushort_t* __restrict__ Wh, const ushort_t* __restrict__ Wl,
    int lw, unsigned bfmask,
    const float* __restrict__ b0, const float* __restrict__ b1,
    const float* __restrict__ b2, const float* __restrict__ b3,
    void* __restrict__ O0, void* __restrict__ O1,
    void* __restrict__ O2, void* __restrict__ O3) {
    int which = blockIdx.y;
    const ushort_t* wh = Wh + (size_t)(lw + which) * 16384;
    const ushort_t* wl = Wl + (size_t)(lw + which) * 16384;
    const float* bias = (which == 0) ? b0 : (which == 1) ? b1 : (which == 2) ? b2 : b3;
    void*        Osel = (which == 0) ? O0 : (which == 1) ? O1 : (which == 2) ? O2 : O3;
    bool obf = (bfmask >> which) & 1;
    float*    Of = (float*)Osel;
    ushort_t* Ob = (ushort_t*)Osel;

    int w = threadIdx.x >> 6;
    int lane = threadIdx.x & 63;
    int quad = lane >> 4, ln = lane & 15;
    int n0 = w * 32;

    // weight fragments resident in VGPRs for the whole block
    bf16x8 bh[2][4], bl[2][4];
#pragma unroll
    for (int ct = 0; ct < 2; ++ct)
#pragma unroll
        for (int kc = 0; kc < 4; ++kc) {
            int addr = (n0 + ct * 16 + ln) * 128 + kc * 32 + quad * 8;
            bh[ct][kc] = *(const bf16x8*)(wh + addr);
            bl[ct][kc] = *(const bf16x8*)(wl + addr);
        }
    float bias0 = bias[n0 + ln];
    float bias1 = bias[n0 + 16 + ln];

    int rowBase = blockIdx.x * 256;
    bf16x8 ah[2][4], al[2][4];   // double-buffered A fragments

    {   // prologue: load row 0
        int rm = min(rowBase + ln, Nn - 1);
        size_t ab = (size_t)rm * 128 + quad * 8;
#pragma unroll
        for (int kc = 0; kc < 4; ++kc) {
            ah[0][kc] = *(const bf16x8*)(Xh + ab + kc * 32);
            al[0][kc] = *(const bf16x8*)(Xl + ab + kc * 32);
        }
    }

#pragma unroll 4
    for (int r = 0; r < 16; ++r) {
        const int cur = r & 1, nxt = cur ^ 1;
        if (r < 15) {       // prefetch row r+1 while computing row r
            int rm = min(rowBase + (r + 1) * 16 + ln, Nn - 1);
            size_t ab = (size_t)rm * 128 + quad * 8;
#pragma unroll
            for (int kc = 0; kc < 4; ++kc) {
                ah[nxt][kc] = *(const bf16x8*)(Xh + ab + kc * 32);
                al[nxt][kc] = *(const bf16x8*)(Xl + ab + kc * 32);
            }
        }
        f32x4 acc00 = {0.f,0.f,0.f,0.f}, acc01 = {0.f,0.f,0.f,0.f};
        f32x4 acc10 = {0.f,0.f,0.f,0.f}, acc11 = {0.f,0.f,0.f,0.f};
#pragma unroll
        for (int kc = 0; kc < 2; ++kc) {
            int k2 = kc + 2;
            acc00 = __builtin_amdgcn_mfma_f32_16x16x32_bf16(ah[cur][kc], bh[0][kc], acc00, 0, 0, 0);
            acc01 = __builtin_amdgcn_mfma_f32_16x16x32_bf16(ah[cur][kc], bh[1][kc], acc01, 0, 0, 0);
            acc10 = __builtin_amdgcn_mfma_f32_16x16x32_bf16(ah[cur][k2], bh[0][k2], acc10, 0, 0, 0);
            acc11 = __builtin_amdgcn_mfma_f32_16x16x32_bf16(ah[cur][k2], bh[1][k2], acc11, 0, 0, 0);
            acc00 = __builtin_amdgcn_mfma_f32_16x16x32_bf16(ah[cur][kc], bl[0][kc], acc00, 0, 0, 0);
            acc01 = __builtin_amdgcn_mfma_f32_16x16x32_bf16(ah[cur][kc], bl[1][kc], acc01, 0, 0, 0);
            acc10 = __builtin_amdgcn_mfma_f32_16x16x32_bf16(ah[cur][k2], bl[0][k2], acc10, 0, 0, 0);
            acc11 = __builtin_amdgcn_mfma_f32_16x16x32_bf16(ah[cur][k2], bl[1][k2], acc11, 0, 0, 0);
            acc00 = __builtin_amdgcn_mfma_f32_16x16x32_bf16(al[cur][kc], bh[0][kc], acc00, 0, 0, 0);
            acc01 = __builtin_amdgcn_mfma_f32_16x16x32_bf16(al[cur][kc], bh[1][kc], acc01, 0, 0, 0);
            acc10 = __builtin_amdgcn_mfma_f32_16x16x32_bf16(al[cur][k2], bh[0][k2], acc10, 0, 0, 0);
            acc11 = __builtin_amdgcn_mfma_f32_16x16x32_bf16(al[cur][k2], bl[1][k2], acc11, 0, 0, 0);
        }
        int m0 = rowBase + r * 16;
        int orow0 = m0 + quad * 4;
        bool full = (orow0 + 3) < Nn;
#pragma unroll
        for (int reg = 0; reg < 4; ++reg) {
            int orow = orow0 + reg;
            if (full || orow < Nn) {
                size_t ob = (size_t)orow * 128;
                float o0 = acc00[reg] + acc10[reg] + bias0;
                float o1 = acc01[reg] + acc11[reg] + bias1;
                if (obf) {
                    Ob[ob + n0 + ln]      = f2bf(o0);
                    Ob[ob + n0 + 16 + ln] = f2bf(o1);
                } else {
                    Of[ob + n0 + ln]      = o0;
                    Of[ob + n0 + 16 + ln] = o1;
                }
            }
        }
    }
}

// ---------------- fused per-node attention ----------------
// One 64-lane wave per node: 4 groups x 16 lanes, lane gl holds dims
// [gl*8, gl*8+8). write_split=1 -> emit split-bf16 (Xh/Xl) for next layer's
// GEMM (saves the convx round-trip); write_split=0 -> fp32 h for pooling.

constexpr int CHUNK = 128;

__global__ __launch_bounds__(256) void attn_kernel(const float* __restrict__ q,
                                                   const ushort_t* __restrict__ k,
                                                   const ushort_t* __restrict__ v,
                                                   const float* __restrict__ s,
                                                   const int* __restrict__ offsets,
                                                   const int* __restrict__ sorted_src,
                                                   float* __restrict__ hf,
                                                   ushort_t* __restrict__ oh,
                                                   ushort_t* __restrict__ ol,
                                                   int write_split) {
    __shared__ float astash[4][CHUNK];
    int wslot = threadIdx.x >> 6;
    int wid = blockIdx.x * 4 + wslot;
    if (wid >= Nn) return;
    int lane = threadIdx.x & 63;
    int g = lane >> 4;           // edge parity group 0..3
    int gl = lane & 15;          // dim chunk within row
    const float4* qrow = (const float4*)(q + (size_t)wid * Dd);
    float4 q0 = qrow[gl * 2];
    float4 q1 = qrow[gl * 2 + 1];
    int beg = offsets[wid], end = offsets[wid + 1];

    float m = -INFINITY, l = 0.f;
    float acc[8];
#pragma unroll
    for (int j = 0; j < 8; ++j) acc[j] = 0.f;

    for (int cbeg = beg; cbeg < end; cbeg += CHUNK) {
        int cend = min(cbeg + CHUNK, end);
        float cm = -INFINITY;
        // pass 1: scores
        for (int e = cbeg + g; e < cend; e += 4) {
            int sidx = sorted_src[e];
            ushort8 kv = *(const ushort8*)(k + (size_t)sidx * Dd + gl * 8);
            float part = q0.x * bf2f(kv[0]) + q0.y * bf2f(kv[1]) +
                         q0.z * bf2f(kv[2]) + q0.w * bf2f(kv[3]) +
                         q1.x * bf2f(kv[4]) + q1.y * bf2f(kv[5]) +
                         q1.z * bf2f(kv[6]) + q1.w * bf2f(kv[7]);
#pragma unroll
            for (int off = 8; off > 0; off >>= 1) part += __shfl_xor(part, off, 64);
            float a = part * SCALE;
            if (gl == 0) astash[wslot][e - cbeg] = a;
            cm = fmaxf(cm, a);
        }
        cm = fmaxf(cm, __shfl_xor(cm, 16, 64));
        cm = fmaxf(cm, __shfl_xor(cm, 32, 64));
        float mn = fmaxf(m, cm);
        float sc = (m > -INFINITY) ? __expf(m - mn) : 0.f;
        l *= sc;
#pragma unroll
        for (int j = 0; j < 8; ++j) acc[j] *= sc;
        // pass 2: weights + V accumulation
        for (int e = cbeg + g; e < cend; e += 4) {
            float w = __expf(astash[wslot][e - cbeg] - mn);
            int sidx = sorted_src[e];
            ushort8 vv = *(const ushort8*)(v + (size_t)sidx * Dd + gl * 8);
            l += w;
#pragma unroll
            for (int j = 0; j < 8; ++j) acc[j] += w * bf2f(vv[j]);
        }
        m = mn;
    }

    // combine the 4 groups' partials (dims align across groups at same gl)
    l += __shfl_xor(l, 16, 64);
    l += __shfl_xor(l, 32, 64);
#pragma unroll
    for (int j = 0; j < 8; ++j) {
        acc[j] += __shfl_xor(acc[j], 16, 64);
        acc[j] += __shfl_xor(acc[j], 32, 64);
    }

    if (g == 0) {
        float inv = (l > 0.f) ? (1.0f / l) : 0.f;   // deg==0 -> pure skip
        const float4* srow = (const float4*)(s + (size_t)wid * Dd);
        float4 sk0 = srow[gl * 2];
        float4 sk1 = srow[gl * 2 + 1];
        float ov[8];
        ov[0] = fmaxf(acc[0] * inv + sk0.x, 0.f);
        ov[1] = fmaxf(acc[1] * inv + sk0.y, 0.f);
        ov[2] = fmaxf(acc[2] * inv + sk0.z, 0.f);
        ov[3] = fmaxf(acc[3] * inv + sk0.w, 0.f);
        ov[4] = fmaxf(acc[4] * inv + sk1.x, 0.f);
        ov[5] = fmaxf(acc[5] * inv + sk1.y, 0.f);
        ov[6] = fmaxf(acc[6] * inv + sk1.z, 0.f);
        ov[7] = fmaxf(acc[7] * inv + sk1.w, 0.f);
        if (write_split) {
            ushort8 hh, ll;
#pragma unroll
            for (int j = 0; j < 8; ++j) {
                hh[j] = f2bf(ov[j]);
                ll[j] = f2bf(ov[j] - bf2f(hh[j]));
            }
            *(ushort8*)(oh + (size_t)wid * Dd + gl * 8) = hh;
            *(ushort8*)(ol + (size_t)wid * Dd + gl * 8) = ll;
        } else {
            float4* hrow = (float4*)(hf + (size_t)wid * Dd);
            hrow[gl * 2]     = make_float4(ov[0], ov[1], ov[2], ov[3]);
            hrow[gl * 2 + 1] = make_float4(ov[4], ov[5], ov[6], ov[7]);
        }
    }
}

// ---------------- pooling + classifier ----------------

__global__ __launch_bounds__(256) void bound_kernel(const int* __restrict__ batch,
                                                    int* __restrict__ startg,
                                                    int* __restrict__ endg) {
    int n = blockIdx.x * 256 + threadIdx.x;
    if (n >= Nn) return;
    int g = batch[n];
    if (n == Nn - 1 || batch[n + 1] != g) endg[g] = n + 1;
    if (n == 0 || batch[n - 1] != g) startg[g] = n;
}

__global__ __launch_bounds__(128) void pool_kernel(const float* __restrict__ h,
                                                   const int* __restrict__ batch,
                                                   float* __restrict__ pooled) {
    int c = threadIdx.x;            // 0..127 (column)
    int n0 = blockIdx.x * 128;
    int nend = min(n0 + 128, Nn);
    int curg = batch[n0];           // batch is sorted -> few segments per block
    float sum = 0.f;
    for (int n = n0; n < nend; ++n) {
        int g = batch[n];
        if (g != curg) {
            atomicAdd(&pooled[curg * Dd + c], sum);
            sum = 0.f;
            curg = g;
        }
        sum += h[(size_t)n * Dd + c];
    }
    atomicAdd(&pooled[curg * Dd + c], sum);
}

__global__ __launch_bounds__(64) void mlp_kernel(const float* __restrict__ pooled,
                                                 const int* __restrict__ startg,
                                                 const int* __restrict__ endg,
                                                 const float* __restrict__ Wc1,
                                                 const float* __restrict__ bc1,
                                                 const float* __restrict__ Wc2,
                                                 const float* __restrict__ bc2,
                                                 float* __restrict__ out) {
    __shared__ float pm[128];
    __shared__ float hid[64];
    int g = blockIdx.x, t = threadIdx.x;   // 64 threads
    float cnt = fmaxf((float)(endg[g] - startg[g]), 1.0f);
    float invc = 1.0f / cnt;
    pm[t]      = pooled[g * 128 + t] * invc;
    pm[t + 64] = pooled[g * 128 + 64 + t] * invc;
    __syncthreads();
    float acc = bc1[t];
    for (int i = 0; i < 128; ++i) acc += pm[i] * Wc1[t * 128 + i];
    hid[t] = fmaxf(acc, 0.f);
    __syncthreads();
    if (t < 2) {
        float a = bc2[t];
        for (int i = 0; i < 64; ++i) a += hid[i] * Wc2[t * 64 + i];
        out[g * 2 + t] = a;
    }
}

// ---------------- launch ----------------

extern "C" void kernel_launch(void* const* d_in, const int* in_sizes, int n_in,
                              void* d_out, int out_size, void* d_ws, size_t ws_size,
                              hipStream_t stream) {
    const float* x   = (const float*)d_in[0];
    const int*   ei  = (const int*)d_in[1];
    const int* batch = (const int*)d_in[2];
    const float* W[2][4];
    const float* B[2][4];
    for (int l = 0; l < 2; ++l) {
        for (int j = 0; j < 4; ++j) W[l][j] = (const float*)d_in[3 + l * 8 + j];
        for (int j = 0; j < 4; ++j) B[l][j] = (const float*)d_in[3 + l * 8 + 4 + j];
    }
    const float* Wc1 = (const float*)d_in[19];
    const float* bc1 = (const float*)d_in[20];
    const float* Wc2 = (const float*)d_in[21];
    const float* bc2 = (const float*)d_in[22];
    float* out = (float*)d_out;

    const int* src = ei;        // edge_index[0]
    const int* dst = ei + Ee;   // edge_index[1]

    char* p = (char*)d_ws;
    auto alloc = [&](size_t bytes) {
        void* r = (void*)p;
        p += (bytes + 255) & ~(size_t)255;
        return r;
    };
    float*    q  = (float*)alloc((size_t)Nn * Dd * 4);
    ushort_t* kk = (ushort_t*)alloc((size_t)Nn * Dd * 2);   // bf16
    ushort_t* vv = (ushort_t*)alloc((size_t)Nn * Dd * 2);   // bf16
    float*    ss = (float*)alloc((size_t)Nn * Dd * 4);
    float*    h  = (float*)alloc((size_t)Nn * Dd * 4);
    ushort_t* Xh = (ushort_t*)alloc((size_t)Nn * Dd * 2);
    ushort_t* Xl = (ushort_t*)alloc((size_t)Nn * Dd * 2);
    ushort_t* Wh = (ushort_t*)alloc((size_t)8 * 16384 * 2);
    ushort_t* Wl = (ushort_t*)alloc((size_t)8 * 16384 * 2);
    char* zbase = p;  // region zeroed each launch
    int*   counts = (int*)alloc(Nn * 4);
    int*   startg = (int*)alloc(Gg * 4);
    int*   endg   = (int*)alloc(Gg * 4);
    float* pooled = (float*)alloc(Gg * Dd * 4);
    size_t zbytes = (size_t)(p - zbase);
    int* offsets    = (int*)alloc((size_t)(Nn + 1) * 4);
    int* cursor     = (int*)alloc(Nn * 4);
    int* blockSums  = (int*)alloc(256 * 4);
    int* sorted_src = (int*)alloc((size_t)Ee * 4);

    hipMemsetAsync(zbase, 0, zbytes, stream);

    constexpr int NB = (Nn + 255) / 256;  // 196 scan blocks
    hist_kernel<<<(Ee + 255) / 256, 256, 0, stream>>>(dst, counts);
    scan1_kernel<<<NB, 256, 0, stream>>>(counts, offsets, blockSums);
    scan2_kernel<<<1, 256, 0, stream>>>(blockSums, NB);
    scan3_kernel<<<NB, 256, 0, stream>>>(offsets, blockSums, cursor);
    scatter_kernel<<<(Ee + 255) / 256, 256, 0, stream>>>(src, dst, cursor, sorted_src);

    convw_kernel<<<128, 256, 0, stream>>>(W[0][0], W[0][1], W[0][2], W[0][3],
                                          W[1][0], W[1][1], W[1][2], W[1][3], Wh, Wl);

    constexpr int N4 = Nn * Dd / 4;
    dim3 ggrid((Nn + 255) / 256, 4);
    constexpr unsigned BFMASK = 0b0110;   // k (1) and v (2) in bf16

    // layer 0
    convx_kernel<<<(N4 + 255) / 256, 256, 0, stream>>>(x, Xh, Xl, N4);
    gemm_mfma_kernel<<<ggrid, 256, 0, stream>>>(Xh, Xl, Wh, Wl, 0, BFMASK,
                                                B[0][0], B[0][1], B[0][2], B[0][3],
                                                q, kk, vv, ss);
    // layer-1 attn writes split-bf16 h straight into Xh/Xl (no convx needed)
    attn_kernel<<<(Nn + 3) / 4, 256, 0, stream>>>(q, kk, vv, ss, offsets, sorted_src,
                                                  h, Xh, Xl, 1);
    // layer 1
    gemm_mfma_kernel<<<ggrid, 256, 0, stream>>>(Xh, Xl, Wh, Wl, 4, BFMASK,
                                                B[1][0], B[1][1], B[1][2], B[1][3],
                                                q, kk, vv, ss);
    attn_kernel<<<(Nn + 3) / 4, 256, 0, stream>>>(q, kk, vv, ss, offsets, sorted_src,
                                                  h, Xh, Xl, 0);

    bound_kernel<<<(Nn + 255) / 256, 256, 0, stream>>>(batch, startg, endg);
    pool_kernel<<<(Nn + 127) / 128, 128, 0, stream>>>(h, batch, pooled);
    mlp_kernel<<<Gg, 64, 0, stream>>>(pooled, startg, endg, Wc1, bc1, Wc2, bc2, out);
}